// Round 8
// baseline (356.043 us; speedup 1.0000x reference)
//
#include <hip/hip_runtime.h>
#include <hip/hip_bf16.h>

// Problem constants (fixed by harness setup_inputs).
#define S_LEN  2048
#define DMODEL 1024
#define NHEADS 16
#define DHEAD  64
#define TOKENS 4096   // B*S
#define QSCALE 0.04508422f   // (1/32) * log2(e): scores come out in log2 domain

typedef __attribute__((ext_vector_type(8))) short bf16x8;
typedef __attribute__((ext_vector_type(4))) float f32x4;

template <int M> struct IC { static constexpr int value = M; };

__device__ __forceinline__ float bf2f(unsigned short b) {
    union { unsigned u; float f; } v; v.u = ((unsigned)b) << 16;
    return v.f;
}
__device__ __forceinline__ unsigned cvt_pk_bf16(float lo, float hi) {
    unsigned r;
    asm("v_cvt_pk_bf16_f32 %0, %1, %2" : "=v"(r) : "v"(lo), "v"(hi));
    return r;
}
__device__ __forceinline__ unsigned short f2bf1(float x) {
    return (unsigned short)cvt_pk_bf16(x, x);
}
// wave-local LDS ordering fence (guards wave-private T/P roundtrips).
__device__ __forceinline__ void lds_fence() {
    asm volatile("s_waitcnt lgkmcnt(0)" ::: "memory");
    __builtin_amdgcn_sched_barrier(0);
}
// global -> LDS DMA, 16B per lane. LDS dest = wave-uniform base + lane*16;
// global src is per-lane (enables source-side swizzle).
__device__ __forceinline__ void gload_lds16(const void* g, void* l) {
    __builtin_amdgcn_global_load_lds(
        (const __attribute__((address_space(1))) void*)g,
        (__attribute__((address_space(3))) void*)l, 16, 0, 0);
}

// ---------------------------------------------------------------------------
// Kernel 1: fused 4-way projection GEMM.  out = X @ W^T + b  (bf16).
// z=0 (q): scaled by QSCALE, layout [BH][S][64]
// z=1 (k), z=3 (p): layout [BH][S][64]
// z=2 (v): layout [BH][64][S]  (transposed, packed b64 stores)
// ---------------------------------------------------------------------------
__global__ __launch_bounds__(256) void proj_gemm(
    const float* __restrict__ x0, const float* __restrict__ x1,
    const float* __restrict__ x2, const float* __restrict__ x3,
    const float* __restrict__ w0, const float* __restrict__ w1,
    const float* __restrict__ w2, const float* __restrict__ w3,
    const float* __restrict__ b0, const float* __restrict__ b1,
    const float* __restrict__ b2, const float* __restrict__ b3,
    unsigned short* __restrict__ o0, unsigned short* __restrict__ o1,
    unsigned short* __restrict__ o2, unsigned short* __restrict__ o3)
{
    const int z = blockIdx.z;
    const float* X  = (z == 0) ? x0 : (z == 1) ? x1 : (z == 2) ? x2 : x3;
    const float* W  = (z == 0) ? w0 : (z == 1) ? w1 : (z == 2) ? w2 : w3;
    const float* Bv = (z == 0) ? b0 : (z == 1) ? b1 : (z == 2) ? b2 : b3;
    unsigned short* O = (z == 0) ? o0 : (z == 1) ? o1 : (z == 2) ? o2 : o3;

    __shared__ __align__(16) unsigned short At[128 * 40];
    __shared__ __align__(16) unsigned short Bt[128 * 40];

    const int tid  = threadIdx.x;
    const int lane = tid & 63;
    const int w    = tid >> 6;
    const int wr   = w & 1, wc = w >> 1;
    const int m0   = blockIdx.x * 128;
    const int n0   = blockIdx.y * 128;
    const int l16  = lane & 15, lq = lane >> 4;

    f32x4 acc[4][4];
    #pragma unroll
    for (int i = 0; i < 4; i++)
        #pragma unroll
        for (int j = 0; j < 4; j++) acc[i][j] = (f32x4){0.f, 0.f, 0.f, 0.f};

    for (int k0 = 0; k0 < DMODEL; k0 += 32) {
        __syncthreads();
        #pragma unroll
        for (int i = 0; i < 4; i++) {
            int e = tid + i * 256;
            int row = e >> 3, cg = e & 7;
            float4 va = *(const float4*)&X[(long)(m0 + row) * DMODEL + k0 + cg * 4];
            uint2 ua; ua.x = cvt_pk_bf16(va.x, va.y); ua.y = cvt_pk_bf16(va.z, va.w);
            *(uint2*)&At[row * 40 + cg * 4] = ua;
            float4 vb = *(const float4*)&W[(long)(n0 + row) * DMODEL + k0 + cg * 4];
            uint2 ub; ub.x = cvt_pk_bf16(vb.x, vb.y); ub.y = cvt_pk_bf16(vb.z, vb.w);
            *(uint2*)&Bt[row * 40 + cg * 4] = ub;
        }
        __syncthreads();
        bf16x8 af[4], bfr[4];
        #pragma unroll
        for (int f = 0; f < 4; f++) {
            af[f]  = *(const bf16x8*)&At[(64 * wr + 16 * f + l16) * 40 + 8 * lq];
            bfr[f] = *(const bf16x8*)&Bt[(64 * wc + 16 * f + l16) * 40 + 8 * lq];
        }
        #pragma unroll
        for (int i = 0; i < 4; i++)
            #pragma unroll
            for (int j = 0; j < 4; j++)
                acc[i][j] = __builtin_amdgcn_mfma_f32_16x16x32_bf16(af[i], bfr[j], acc[i][j], 0, 0, 0);
    }

    #pragma unroll
    for (int j = 0; j < 4; j++) {
        int n_g = n0 + 64 * wc + 16 * j + l16;
        float bias = Bv[n_g];
        int h = n_g >> 6, dh = n_g & 63;
        if (z == 2) {
            #pragma unroll
            for (int i = 0; i < 4; i++) {
                int m_g = m0 + 64 * wr + 16 * i + 4 * lq;
                int b = m_g >> 11, s = m_g & (S_LEN - 1);
                uint2 u;
                u.x = cvt_pk_bf16(acc[i][j][0] + bias, acc[i][j][1] + bias);
                u.y = cvt_pk_bf16(acc[i][j][2] + bias, acc[i][j][3] + bias);
                *(uint2*)&O[(long)(((b * NHEADS + h) * DHEAD) + dh) * S_LEN + s] = u;
            }
        } else {
            float scale = (z == 0) ? QSCALE : 1.0f;
            #pragma unroll
            for (int i = 0; i < 4; i++) {
                #pragma unroll
                for (int r = 0; r < 4; r++) {
                    int m_g = m0 + 64 * wr + 16 * i + 4 * lq + r;
                    int b = m_g >> 11, s = m_g & (S_LEN - 1);
                    O[(long)(((b * NHEADS + h) * S_LEN) + s) * DHEAD + dh] =
                        f2bf1((acc[i][j][r] + bias) * scale);
                }
            }
        }
    }
}

// ---------------------------------------------------------------------------
// Kernel 2: fused relative-position flash attention, 4 waves, QB=64.
// ONE barrier per tile: Kb double-buffered, P2 ring 256 rows -> the stage for
// tile ct+1 (issued at tile-ct start) never collides with tile ct's reads;
// the end-of-tile __syncthreads (implicit vmcnt/lgkmcnt drain) covers all
// cross-wave hazards. V direct loads issued BEFORE stage gloads so PV's
// vmcnt wait doesn't FIFO-drain the in-flight stages.
// Compute paths (T roundtrip, LDS P roundtrip, softmax) = round-5 verified.
// ---------------------------------------------------------------------------
__global__ __launch_bounds__(256, 3) void rel_attn(
    const unsigned short* __restrict__ Q,    // [BH][S][64] bf16, pre-scaled
    const unsigned short* __restrict__ K,    // [BH][S][64]
    const unsigned short* __restrict__ VT,   // [BH][64][S]
    const unsigned short* __restrict__ P,    // [BH][S][64] plain p table
    unsigned short* __restrict__ CTX)        // [B][S][H][64] bf16
{
    __shared__ __align__(16) unsigned short Kb[2 * 64 * 64];  // 16 KB dbuf
    __shared__ __align__(16) unsigned short P2b[256 * 64];    // 32 KB ring
    __shared__ __align__(16) unsigned short WPb[4 * 1344];    // per-wave T(16x84)/P(16x72) alias

    const int tid  = threadIdx.x;
    const int lane = tid & 63;
    const int w    = tid >> 6;
    const int l16  = lane & 15;
    const int lq   = lane >> 4;

    const int wg = ((blockIdx.x & 7) << 7) + (blockIdx.x >> 3);  // XCD swizzle
    const int qt = wg & 31;
    const int bh = wg >> 5;
    const int q0 = qt << 6;
    const long baseQK = (long)bh * (S_LEN * DHEAD);
    const int qi_l = 16 * w + l16;

    const unsigned short* Kbh = K + baseQK;
    const unsigned short* Pbh = P + baseQK;
    const unsigned short* Vl  = VT + baseQK + (long)l16 * S_LEN + 8 * lq;

    // swizzled granule offsets for fragment reads (shorts); row&7 == l16&7
    const int gx0 = ((0 + lq) ^ (l16 & 7)) * 8;
    const int gx1 = ((4 + lq) ^ (l16 & 7)) * 8;

    // hoisted Q fragments: rows qi_l and qi_l+1
    bf16x8 qf0[2], qf1[2];
    {
        const unsigned short* qrow = Q + baseQK + (long)(q0 + qi_l) * DHEAD + 8 * lq;
        qf0[0] = *(const bf16x8*)(qrow);
        qf0[1] = *(const bf16x8*)(qrow + 32);
        qf1[0] = *(const bf16x8*)(qrow + DHEAD);
        qf1[1] = *(const bf16x8*)(qrow + DHEAD + 32);
    }

    // staging: 64 rows / 8KB per stage, 2 gloads per thread
    const int srow = lane >> 3;            // row-within-8 == row&7
    const int sgr  = (lane & 7) ^ srow;    // pre-swizzled source granule
    auto stage_K = [&](int kr0, int buf) __attribute__((always_inline)) {
        #pragma unroll
        for (int j = 0; j < 2; ++j) {
            int idx = w * 2 + j;
            const unsigned short* src = Kbh + (long)(kr0 + idx * 8 + srow) * 64 + sgr * 8;
            gload_lds16(src, &Kb[buf * 4096 + idx * 512]);
        }
    };
    auto stage_P2 = [&](int mfirst) __attribute__((always_inline)) {   // mfirst % 64 == 0
        #pragma unroll
        for (int j = 0; j < 2; ++j) {
            int idx = w * 2 + j;
            int m = mfirst + idx * 8 + srow;
            int pr = m - ((m >= 2049) ? 2049 : 0);   // wrap; m==2048 garbage discarded later
            const unsigned short* src = Pbh + (long)pr * 64 + sgr * 8;
            gload_lds16(src, &P2b[((mfirst + idx * 8) & 255) * 64]);
        }
    };

    float mrow = -1e30f, lrow = 0.f;
    f32x4 oacc[4];
    #pragma unroll
    for (int f = 0; f < 4; f++) oacc[f] = (f32x4){0.f, 0.f, 0.f, 0.f};

    unsigned short* tw        = &WPb[w * 1344 + l16 * 84 + 4 * lq];
    const unsigned short* tr  = &WPb[w * 1344 + l16 * 83 + 15 + 4 * lq];
    unsigned short* pw        = &WPb[w * 1344 + l16 * 72 + 4 * lq];
    const unsigned short* prd = &WPb[w * 1344 + l16 * 72 + 8 * lq];

    const int W0 = 1984 - q0;   // lowest P2-window row of tile 0
    stage_K(0, 0);
    stage_P2(W0); stage_P2(W0 + 64);
    __syncthreads();

    // softmax + LDS P roundtrip + PV (round-5 verified path)
    auto finish = [&](float (&sc)[4][4], bf16x8 (&vf)[2][4]) __attribute__((always_inline)) {
        float tmax = sc[0][0];
        #pragma unroll
        for (int fc = 0; fc < 4; ++fc)
            #pragma unroll
            for (int r = 0; r < 4; ++r) tmax = fmaxf(tmax, sc[fc][r]);
        tmax = fmaxf(tmax, __shfl_xor(tmax, 16, 64));
        tmax = fmaxf(tmax, __shfl_xor(tmax, 32, 64));
        float nm = fmaxf(mrow, tmax);
        float alpha = __builtin_amdgcn_exp2f(mrow - nm);
        mrow = nm;
        float pv[4][4];
        float rs = 0.f;
        #pragma unroll
        for (int fc = 0; fc < 4; ++fc)
            #pragma unroll
            for (int r = 0; r < 4; ++r) {
                float p = __builtin_amdgcn_exp2f(sc[fc][r] - nm);
                pv[fc][r] = p;
                rs += p;
            }
        rs += __shfl_xor(rs, 16, 64);
        rs += __shfl_xor(rs, 32, 64);
        lrow = lrow * alpha + rs;
        #pragma unroll
        for (int f = 0; f < 4; f++)
            #pragma unroll
            for (int r = 0; r < 4; r++) oacc[f][r] *= alpha;

        lds_fence();   // this tile's T reads retired before P overwrites alias
        #pragma unroll
        for (int fc = 0; fc < 4; ++fc) {
            uint2 u;
            u.x = cvt_pk_bf16(pv[fc][0], pv[fc][1]);
            u.y = cvt_pk_bf16(pv[fc][2], pv[fc][3]);
            *(uint2*)(pw + 16 * fc) = u;
        }
        lds_fence();
        bf16x8 pfr[2];
        pfr[0] = *(const bf16x8*)(prd);
        pfr[1] = *(const bf16x8*)(prd + 32);

        #pragma unroll
        for (int kk = 0; kk < 2; ++kk)
            #pragma unroll
            for (int fa = 0; fa < 4; ++fa)
                oacc[fa] = __builtin_amdgcn_mfma_f32_16x16x32_bf16(vf[kk][fa], pfr[kk], oacc[fa], 0, 0, 0);
    };

    auto tile_pure = [&](auto mc, int ct, bool dz) __attribute__((always_inline)) {
        constexpr int MODE = decltype(mc)::value;   // 0: c<q, 1: c>q
        const int c0 = ct << 6;
        const int kb_ = (ct & 1) * 4096;
        const int mb = c0 - q0 + 2032 - 16 * w + l16;

        // V fragments first in the vmem queue
        bf16x8 vf[2][4];
        #pragma unroll
        for (int kk = 0; kk < 2; ++kk)
            #pragma unroll
            for (int fa = 0; fa < 4; ++fa)
                vf[kk][fa] = *(const bf16x8*)(Vl + c0 + fa * (16 * S_LEN) + kk * 32);

        // stage next tile (disjoint LDS: K buf^1, ring slots +128..+191)
        if (ct < 31) { stage_K(c0 + 64, (ct & 1) ^ 1); stage_P2(W0 + 128 + 64 * ct); }

        f32x4 cacc[4];
        #pragma unroll
        for (int f = 0; f < 4; f++) cacc[f] = (f32x4){0.f, 0.f, 0.f, 0.f};
        #pragma unroll
        for (int fc = 0; fc < 4; ++fc) {
            bf16x8 k0v = *(const bf16x8*)&Kb[kb_ + (16 * fc + l16) * 64 + gx0];
            bf16x8 k1v = *(const bf16x8*)&Kb[kb_ + (16 * fc + l16) * 64 + gx1];
            cacc[fc] = __builtin_amdgcn_mfma_f32_16x16x32_bf16(k0v, qf0[0], cacc[fc], 0, 0, 0);
            cacc[fc] = __builtin_amdgcn_mfma_f32_16x16x32_bf16(k1v, qf0[1], cacc[fc], 0, 0, 0);
        }

        f32x4 tacc[5];
        #pragma unroll
        for (int g = 0; g < 5; g++) tacc[g] = (f32x4){0.f, 0.f, 0.f, 0.f};
        #pragma unroll
        for (int cg = 0; cg < 5; ++cg) {
            int sb = ((mb + 16 * cg) & 255) * 64;
            bf16x8 p0 = *(const bf16x8*)&P2b[sb + gx0];
            bf16x8 p1 = *(const bf16x8*)&P2b[sb + gx1];
            tacc[cg] = __builtin_amdgcn_mfma_f32_16x16x32_bf16(
                p0, (MODE == 1) ? qf1[0] : qf0[0], tacc[cg], 0, 0, 0);
            tacc[cg] = __builtin_amdgcn_mfma_f32_16x16x32_bf16(
                p1, (MODE == 1) ? qf1[1] : qf0[1], tacc[cg], 0, 0, 0);
        }

        lds_fence();   // prior tile's P reads retired before T overwrites alias
        #pragma unroll
        for (int cg = 0; cg < 5; ++cg) {
            uint2 u;
            u.x = cvt_pk_bf16(tacc[cg][0], tacc[cg][1]);
            u.y = cvt_pk_bf16(tacc[cg][2], tacc[cg][3]);
            *(uint2*)(tw + 16 * cg) = u;
        }
        lds_fence();

        float sc[4][4];
        #pragma unroll
        for (int fc = 0; fc < 4; ++fc)
            #pragma unroll
            for (int r = 0; r < 4; ++r)
                sc[fc][r] = cacc[fc][r] + bf2f(tr[16 * fc + r]);
        if (MODE == 1 && dz && qi_l == 63 && lq == 0)
            sc[0][0] = cacc[0][0];   // c == q+1 position: zero pos term

        finish(sc, vf);
        __syncthreads();   // staged K/ring landed (implicit vmcnt drain) + wave sync
    };

    auto tile_dual = [&](int ct) __attribute__((always_inline)) {
        const int c0 = ct << 6;
        const int kb_ = (ct & 1) * 4096;
        const int mb = c0 - q0 + 2032 - 16 * w + l16;

        if (ct < 31) { stage_K(c0 + 64, (ct & 1) ^ 1); stage_P2(W0 + 128 + 64 * ct); }

        f32x4 cacc[4];
        #pragma unroll
        for (int f = 0; f < 4; f++) cacc[f] = (f32x4){0.f, 0.f, 0.f, 0.f};
        #pragma unroll
        for (int fc = 0; fc < 4; ++fc) {
            bf16x8 k0v = *(const bf16x8*)&Kb[kb_ + (16 * fc + l16) * 64 + gx0];
            bf16x8 k1v = *(const bf16x8*)&Kb[kb_ + (16 * fc + l16) * 64 + gx1];
            cacc[fc] = __builtin_amdgcn_mfma_f32_16x16x32_bf16(k0v, qf0[0], cacc[fc], 0, 0, 0);
            cacc[fc] = __builtin_amdgcn_mfma_f32_16x16x32_bf16(k1v, qf0[1], cacc[fc], 0, 0, 0);
        }

        // pass A (su=0)
        f32x4 tacc[5];
        #pragma unroll
        for (int g = 0; g < 5; g++) tacc[g] = (f32x4){0.f, 0.f, 0.f, 0.f};
        #pragma unroll
        for (int cg = 0; cg < 5; ++cg) {
            int sb = ((mb + 16 * cg) & 255) * 64;
            bf16x8 p0 = *(const bf16x8*)&P2b[sb + gx0];
            bf16x8 p1 = *(const bf16x8*)&P2b[sb + gx1];
            tacc[cg] = __builtin_amdgcn_mfma_f32_16x16x32_bf16(p0, qf0[0], tacc[cg], 0, 0, 0);
            tacc[cg] = __builtin_amdgcn_mfma_f32_16x16x32_bf16(p1, qf0[1], tacc[cg], 0, 0, 0);
        }
        lds_fence();
        #pragma unroll
        for (int cg = 0; cg < 5; ++cg) {
            uint2 u;
            u.x = cvt_pk_bf16(tacc[cg][0], tacc[cg][1]);
            u.y = cvt_pk_bf16(tacc[cg][2], tacc[cg][3]);
            *(uint2*)(tw + 16 * cg) = u;
        }
        lds_fence();
        float v0[4][4];
        #pragma unroll
        for (int fc = 0; fc < 4; ++fc)
            #pragma unroll
            for (int r = 0; r < 4; ++r) v0[fc][r] = bf2f(tr[16 * fc + r]);
        lds_fence();   // v0 reads retired before pass-B T overwrite

        // pass B (su=1)
        f32x4 tb2[5];
        #pragma unroll
        for (int g = 0; g < 5; g++) tb2[g] = (f32x4){0.f, 0.f, 0.f, 0.f};
        #pragma unroll
        for (int cg = 0; cg < 5; ++cg) {
            int sb = ((mb + 16 * cg) & 255) * 64;
            bf16x8 p0 = *(const bf16x8*)&P2b[sb + gx0];
            bf16x8 p1 = *(const bf16x8*)&P2b[sb + gx1];
            tb2[cg] = __builtin_amdgcn_mfma_f32_16x16x32_bf16(p0, qf1[0], tb2[cg], 0, 0, 0);
            tb2[cg] = __builtin_amdgcn_mfma_f32_16x16x32_bf16(p1, qf1[1], tb2[cg], 0, 0, 0);
        }
        #pragma unroll
        for (int cg = 0; cg < 5; ++cg) {
            uint2 u;
            u.x = cvt_pk_bf16(tb2[cg][0], tb2[cg][1]);
            u.y = cvt_pk_bf16(tb2[cg][2], tb2[cg][3]);
            *(uint2*)(tw + 16 * cg) = u;
        }
        lds_fence();

        float sc[4][4];
        #pragma unroll
        for (int fc = 0; fc < 4; ++fc)
            #pragma unroll
            for (int r = 0; r < 4; ++r) {
                float v1 = bf2f(tr[16 * fc + r]);
                int ci = 16 * fc + 4 * lq + r;
                float term = (ci == qi_l + 1) ? 0.f
                           : ((ci > qi_l) ? v1 : v0[fc][r]);
                sc[fc][r] = cacc[fc][r] + term;
            }

        bf16x8 vf[2][4];   // V late here to cap VGPR pressure (1/32 tiles)
        #pragma unroll
        for (int kk = 0; kk < 2; ++kk)
            #pragma unroll
            for (int fa = 0; fa < 4; ++fa)
                vf[kk][fa] = *(const bf16x8*)(Vl + c0 + fa * (16 * S_LEN) + kk * 32);

        finish(sc, vf);
        __syncthreads();
    };

    for (int ct = 0; ct < qt; ++ct) tile_pure(IC<0>{}, ct, false);
    tile_dual(qt);
    if (qt < 31) {
        tile_pure(IC<1>{}, qt + 1, true);
        for (int ct = qt + 2; ct < S_LEN / 64; ++ct) tile_pure(IC<1>{}, ct, false);
    }

    // epilogue: lane owns row q0+qi_l; 4 consecutive dh -> packed 8B stores
    const int b = bh >> 4, h = bh & 15;
    const float rinv = 1.0f / lrow;
    unsigned short* op = CTX + ((long)(b * S_LEN + q0 + qi_l) * NHEADS + h) * DHEAD + 4 * lq;
    #pragma unroll
    for (int fa = 0; fa < 4; ++fa) {
        uint2 u;
        u.x = cvt_pk_bf16(oacc[fa][0] * rinv, oacc[fa][1] * rinv);
        u.y = cvt_pk_bf16(oacc[fa][2] * rinv, oacc[fa][3] * rinv);
        *(uint2*)(op + 16 * fa) = u;
    }
}

// ---------------------------------------------------------------------------
// Kernel 3: output GEMM.  out = ctx(bf16) @ Wo^T + bo, fp32 out.
// ---------------------------------------------------------------------------
__global__ __launch_bounds__(256) void out_gemm(
    const unsigned short* __restrict__ A,
    const float* __restrict__ W,
    const float* __restrict__ Bv,
    float* __restrict__ O)
{
    __shared__ __align__(16) unsigned short At[128 * 40];
    __shared__ __align__(16) unsigned short Bt[128 * 40];

    const int tid  = threadIdx.x;
    const int lane = tid & 63;
    const int w    = tid >> 6;
    const int wr   = w & 1, wc = w >> 1;
    const int m0   = blockIdx.x * 128;
    const int n0   = blockIdx.y * 128;
    const int l16  = lane & 15, lq = lane >> 4;

    f32x4 acc[4][4];
    #pragma unroll
    for (int i = 0; i < 4; i++)
        #pragma unroll
        for (int j = 0; j < 4; j++) acc[i][j] = (f32x4){0.f, 0.f, 0.f, 0.f};

    for (int k0 = 0; k0 < DMODEL; k0 += 32) {
        __syncthreads();
        #pragma unroll
        for (int i = 0; i < 2; i++) {
            int e = tid + i * 256;
            int row = e >> 2, sg = e & 3;
            *(float4*)&At[row * 40 + sg * 8] =
                *(const float4*)&A[(long)(m0 + row) * DMODEL + k0 + sg * 8];
        }
        #pragma unroll
        for (int i = 0; i < 4; i++) {
            int e = tid + i * 256;
            int row = e >> 3, cg = e & 7;
            float4 vb = *(const float4*)&W[(long)(n0 + row) * DMODEL + k0 + cg * 4];
            uint2 ub; ub.x = cvt_pk_bf16(vb.x, vb.y); ub.y = cvt_pk_bf16(vb.z, vb.w);
            *(uint2*)&Bt[row * 40 + cg * 4] = ub;
        }
        __syncthreads();
        bf16x8 af[4], bfr[4];
        #pragma unroll
        for (int f = 0; f < 4; f++) {
            af[f]  = *(const bf16x8*)&At[(64 * wr + 16 * f + l16) * 40 + 8 * lq];
            bfr[f] = *(const bf16x8*)&Bt[(64 * wc + 16 * f + l16) * 40 + 8 * lq];
        }
        #pragma unroll
        for (int i = 0; i < 4; i++)
            #pragma unroll
            for (int j = 0; j < 4; j++)
                acc[i][j] = __builtin_amdgcn_mfma_f32_16x16x32_bf16(af[i], bfr[j], acc[i][j], 0, 0, 0);
    }

    #pragma unroll
    for (int j = 0; j < 4; j++) {
        int n_g = n0 + 64 * wc + 16 * j + l16;
        float bias = Bv[n_g];
        #pragma unroll
        for (int i = 0; i < 4; i++) {
            #pragma unroll
            for (int r = 0; r < 4; r++) {
                int m_g = m0 + 64 * wr + 16 * i + 4 * lq + r;
                O[(long)m_g * DMODEL + n_g] = acc[i][j][r] + bias;
            }
        }
    }
}

// ---------------------------------------------------------------------------
extern "C" void kernel_launch(void* const* d_in, const int* in_sizes, int n_in,
                              void* d_out, int out_size, void* d_ws, size_t ws_size,
                              hipStream_t stream) {
    (void)in_sizes; (void)n_in; (void)out_size; (void)ws_size;
    const float* query = (const float*)d_in[0];
    const float* key_  = (const float*)d_in[1];
    const float* value = (const float*)d_in[2];
    const float* pos   = (const float*)d_in[3];
    const float* Wq = (const float*)d_in[4];  const float* bq = (const float*)d_in[5];
    const float* Wk = (const float*)d_in[6];  const float* bk = (const float*)d_in[7];
    const float* Wv = (const float*)d_in[8];  const float* bv = (const float*)d_in[9];
    const float* Wp = (const float*)d_in[10]; const float* bp = (const float*)d_in[11];
    const float* Wo = (const float*)d_in[12]; const float* bo = (const float*)d_in[13];
    float* out = (float*)d_out;

    const long NE = (long)TOKENS * DMODEL;   // 4,194,304 elements per tensor
    unsigned short* qb = (unsigned short*)d_ws;
    unsigned short* kb = qb + NE;
    unsigned short* vb = kb + NE;            // V^T layout [BH][64][S]
    unsigned short* pb = vb + NE;            // plain p table [BH][S][64]
    unsigned short* cx = pb + NE;            // total ws use: 5 * 8 MB = 40 MB

    proj_gemm<<<dim3(32, 8, 4), 256, 0, stream>>>(
        query, key_, value, pos, Wq, Wk, Wv, Wp, bq, bk, bv, bp, qb, kb, vb, pb);
    rel_attn<<<1024, 256, 0, stream>>>(qb, kb, vb, pb, cx);
    out_gemm<<<dim3(32, 8), 256, 0, stream>>>(cx, Wo, bo, out);
}

// Round 9
// 251.477 us; speedup vs baseline: 1.4158x; 1.4158x over previous
//
#include <hip/hip_runtime.h>
#include <hip/hip_bf16.h>

// Problem constants (fixed by harness setup_inputs).
#define S_LEN  2048
#define DMODEL 1024
#define NHEADS 16
#define DHEAD  64
#define TOKENS 4096   // B*S
#define QSCALE 0.04508422f   // (1/32) * log2(e): scores come out in log2 domain

typedef __attribute__((ext_vector_type(8))) short bf16x8;
typedef __attribute__((ext_vector_type(4))) float f32x4;

template <int M> struct IC { static constexpr int value = M; };

__device__ __forceinline__ float bf2f(unsigned short b) {
    union { unsigned u; float f; } v; v.u = ((unsigned)b) << 16;
    return v.f;
}
__device__ __forceinline__ unsigned cvt_pk_bf16(float lo, float hi) {
    unsigned r;
    asm("v_cvt_pk_bf16_f32 %0, %1, %2" : "=v"(r) : "v"(lo), "v"(hi));
    return r;
}
__device__ __forceinline__ unsigned short f2bf1(float x) {
    return (unsigned short)cvt_pk_bf16(x, x);
}
// wave-local LDS ordering fence (guards wave-private T/P roundtrips).
__device__ __forceinline__ void lds_fence() {
    asm volatile("s_waitcnt lgkmcnt(0)" ::: "memory");
    __builtin_amdgcn_sched_barrier(0);
}
// global -> LDS DMA, 16B per lane. LDS dest = wave-uniform base + lane*16;
// global src is per-lane (enables source-side swizzle).
__device__ __forceinline__ void gload_lds16(const void* g, void* l) {
    __builtin_amdgcn_global_load_lds(
        (const __attribute__((address_space(1))) void*)g,
        (__attribute__((address_space(3))) void*)l, 16, 0, 0);
}

// ---------------------------------------------------------------------------
// Kernel 1: fused 4-way projection GEMM.  out = X @ W^T + b  (bf16).
// z=0 (q): scaled by QSCALE, layout [BH][S][64]
// z=1 (k), z=3 (p): layout [BH][S][64]
// z=2 (v): layout [BH][64][S]  (transposed, packed b64 stores)
// ---------------------------------------------------------------------------
__global__ __launch_bounds__(256) void proj_gemm(
    const float* __restrict__ x0, const float* __restrict__ x1,
    const float* __restrict__ x2, const float* __restrict__ x3,
    const float* __restrict__ w0, const float* __restrict__ w1,
    const float* __restrict__ w2, const float* __restrict__ w3,
    const float* __restrict__ b0, const float* __restrict__ b1,
    const float* __restrict__ b2, const float* __restrict__ b3,
    unsigned short* __restrict__ o0, unsigned short* __restrict__ o1,
    unsigned short* __restrict__ o2, unsigned short* __restrict__ o3)
{
    const int z = blockIdx.z;
    const float* X  = (z == 0) ? x0 : (z == 1) ? x1 : (z == 2) ? x2 : x3;
    const float* W  = (z == 0) ? w0 : (z == 1) ? w1 : (z == 2) ? w2 : w3;
    const float* Bv = (z == 0) ? b0 : (z == 1) ? b1 : (z == 2) ? b2 : b3;
    unsigned short* O = (z == 0) ? o0 : (z == 1) ? o1 : (z == 2) ? o2 : o3;

    __shared__ __align__(16) unsigned short At[128 * 40];
    __shared__ __align__(16) unsigned short Bt[128 * 40];

    const int tid  = threadIdx.x;
    const int lane = tid & 63;
    const int w    = tid >> 6;
    const int wr   = w & 1, wc = w >> 1;
    const int m0   = blockIdx.x * 128;
    const int n0   = blockIdx.y * 128;
    const int l16  = lane & 15, lq = lane >> 4;

    f32x4 acc[4][4];
    #pragma unroll
    for (int i = 0; i < 4; i++)
        #pragma unroll
        for (int j = 0; j < 4; j++) acc[i][j] = (f32x4){0.f, 0.f, 0.f, 0.f};

    for (int k0 = 0; k0 < DMODEL; k0 += 32) {
        __syncthreads();
        #pragma unroll
        for (int i = 0; i < 4; i++) {
            int e = tid + i * 256;
            int row = e >> 3, cg = e & 7;
            float4 va = *(const float4*)&X[(long)(m0 + row) * DMODEL + k0 + cg * 4];
            uint2 ua; ua.x = cvt_pk_bf16(va.x, va.y); ua.y = cvt_pk_bf16(va.z, va.w);
            *(uint2*)&At[row * 40 + cg * 4] = ua;
            float4 vb = *(const float4*)&W[(long)(n0 + row) * DMODEL + k0 + cg * 4];
            uint2 ub; ub.x = cvt_pk_bf16(vb.x, vb.y); ub.y = cvt_pk_bf16(vb.z, vb.w);
            *(uint2*)&Bt[row * 40 + cg * 4] = ub;
        }
        __syncthreads();
        bf16x8 af[4], bfr[4];
        #pragma unroll
        for (int f = 0; f < 4; f++) {
            af[f]  = *(const bf16x8*)&At[(64 * wr + 16 * f + l16) * 40 + 8 * lq];
            bfr[f] = *(const bf16x8*)&Bt[(64 * wc + 16 * f + l16) * 40 + 8 * lq];
        }
        #pragma unroll
        for (int i = 0; i < 4; i++)
            #pragma unroll
            for (int j = 0; j < 4; j++)
                acc[i][j] = __builtin_amdgcn_mfma_f32_16x16x32_bf16(af[i], bfr[j], acc[i][j], 0, 0, 0);
    }

    #pragma unroll
    for (int j = 0; j < 4; j++) {
        int n_g = n0 + 64 * wc + 16 * j + l16;
        float bias = Bv[n_g];
        int h = n_g >> 6, dh = n_g & 63;
        if (z == 2) {
            #pragma unroll
            for (int i = 0; i < 4; i++) {
                int m_g = m0 + 64 * wr + 16 * i + 4 * lq;
                int b = m_g >> 11, s = m_g & (S_LEN - 1);
                uint2 u;
                u.x = cvt_pk_bf16(acc[i][j][0] + bias, acc[i][j][1] + bias);
                u.y = cvt_pk_bf16(acc[i][j][2] + bias, acc[i][j][3] + bias);
                *(uint2*)&O[(long)(((b * NHEADS + h) * DHEAD) + dh) * S_LEN + s] = u;
            }
        } else {
            float scale = (z == 0) ? QSCALE : 1.0f;
            #pragma unroll
            for (int i = 0; i < 4; i++) {
                #pragma unroll
                for (int r = 0; r < 4; r++) {
                    int m_g = m0 + 64 * wr + 16 * i + 4 * lq + r;
                    int b = m_g >> 11, s = m_g & (S_LEN - 1);
                    O[(long)(((b * NHEADS + h) * S_LEN) + s) * DHEAD + dh] =
                        f2bf1((acc[i][j][r] + bias) * scale);
                }
            }
        }
    }
}

// ---------------------------------------------------------------------------
// Kernel 2: fused relative-position flash attention, 8 waves, QB=128.
// Grid 512 (XCD-swizzled) = exactly 2 blocks/CU resident. r6-verified tile
// arithmetic; V now staged through double-buffered LDS (removes the 32-VGPR
// vf live range that caused r6's spills). Kb single-buffered (staged after
// mid-barrier), P2 ring 256 rows (+64/tile). Per-wave T/P alias region.
// Diagonal tiles ct in {2qt, 2qt+1}: dual pos pass with per-element select.
// ---------------------------------------------------------------------------
__global__ __launch_bounds__(512, 4) void rel_attn(
    const unsigned short* __restrict__ Q,    // [BH][S][64] bf16, pre-scaled
    const unsigned short* __restrict__ K,    // [BH][S][64]
    const unsigned short* __restrict__ VT,   // [BH][64][S]
    const unsigned short* __restrict__ P,    // [BH][S][64] plain p table
    unsigned short* __restrict__ CTX)        // [B][S][H][64] bf16
{
    __shared__ __align__(16) unsigned short Kb[64 * 64];      // 8 KB
    __shared__ __align__(16) unsigned short Vb[2 * 64 * 64];  // 16 KB dbuf
    __shared__ __align__(16) unsigned short P2b[256 * 64];    // 32 KB ring
    __shared__ __align__(16) unsigned short WPb[8 * 1344];    // per-wave T(16x84)/P(16x72)

    const int tid  = threadIdx.x;
    const int lane = tid & 63;
    const int w    = tid >> 6;          // 0..7
    const int l16  = lane & 15;
    const int lq   = lane >> 4;

    const int wg = ((blockIdx.x & 7) << 6) | (blockIdx.x >> 3);  // XCD swizzle (512 = 8*64)
    const int qt = wg & 15;
    const int bh = wg >> 4;
    const int q0 = qt << 7;             // 128 q-rows per block
    const long baseQK = (long)bh * (S_LEN * DHEAD);
    const int gq_rel = 16 * w + l16;    // q-row within block (0..127)

    const unsigned short* Kbh = K + baseQK;
    const unsigned short* Pbh = P + baseQK;
    const unsigned short* Vbh = VT + baseQK;

    // swizzled granule offsets for fragment reads (shorts); row&7 == l16&7
    const int gx0 = ((0 + lq) ^ (l16 & 7)) * 8;
    const int gx1 = ((4 + lq) ^ (l16 & 7)) * 8;

    // hoisted Q fragments: rows q0+gq_rel and +1 (row-2048 OOB read stays in
    // ws and only feeds pass-B values the select discards)
    bf16x8 qf0[2], qf1[2];
    {
        const unsigned short* qrow = Q + baseQK + (long)(q0 + gq_rel) * DHEAD + 8 * lq;
        qf0[0] = *(const bf16x8*)(qrow);
        qf0[1] = *(const bf16x8*)(qrow + 32);
        qf1[0] = *(const bf16x8*)(qrow + DHEAD);
        qf1[1] = *(const bf16x8*)(qrow + DHEAD + 32);
    }

    // staging: 64 rows / 8KB per stage = 1 gload per thread (512 x 16B)
    const int srow = lane >> 3;            // row-within-8 == row&7
    const int sgr  = (lane & 7) ^ srow;    // pre-swizzled source granule
    auto stage_K = [&](int kr0) __attribute__((always_inline)) {
        const unsigned short* src = Kbh + (long)(kr0 + w * 8 + srow) * 64 + sgr * 8;
        gload_lds16(src, &Kb[(w * 8) * 64]);
    };
    auto stage_V = [&](int c0, int buf) __attribute__((always_inline)) {
        // V tile rows = dh (0..63), row data = VT[bh][dh][c0..c0+63]
        const unsigned short* src = Vbh + (long)(w * 8 + srow) * S_LEN + c0 + sgr * 8;
        gload_lds16(src, &Vb[buf * 4096 + (w * 8) * 64]);
    };
    auto stage_P2 = [&](int mfirst) __attribute__((always_inline)) {   // mfirst % 64 == 0
        int m = mfirst + w * 8 + srow;
        int pr = m - ((m >= 2049) ? 2049 : 0);   // wrap; m==2048 garbage discarded later
        const unsigned short* src = Pbh + (long)pr * 64 + sgr * 8;
        gload_lds16(src, &P2b[(((mfirst & 255)) + w * 8) * 64]);
    };

    float mrow = -1e30f, lrow = 0.f;
    f32x4 oacc[4];
    #pragma unroll
    for (int f = 0; f < 4; f++) oacc[f] = (f32x4){0.f, 0.f, 0.f, 0.f};

    unsigned short* tw        = &WPb[w * 1344 + l16 * 84 + 4 * lq];
    const unsigned short* tr  = &WPb[w * 1344 + l16 * 83 + 15 + 4 * lq];
    unsigned short* pw        = &WPb[w * 1344 + l16 * 72 + 4 * lq];
    const unsigned short* prd = &WPb[w * 1344 + l16 * 72 + 8 * lq];

    const int W0 = 1920 - q0;   // lowest P2-window row of tile 0
    stage_K(0);
    stage_V(0, 0);
    stage_P2(W0); stage_P2(W0 + 64); stage_P2(W0 + 128);
    __syncthreads();

    // softmax + LDS P roundtrip + PV (V fragments from LDS)
    auto finish = [&](float (&sc)[4][4], const unsigned short* vbuf) __attribute__((always_inline)) {
        float tmax = sc[0][0];
        #pragma unroll
        for (int fc = 0; fc < 4; ++fc)
            #pragma unroll
            for (int r = 0; r < 4; ++r) tmax = fmaxf(tmax, sc[fc][r]);
        tmax = fmaxf(tmax, __shfl_xor(tmax, 16, 64));
        tmax = fmaxf(tmax, __shfl_xor(tmax, 32, 64));
        float nm = fmaxf(mrow, tmax);
        float alpha = __builtin_amdgcn_exp2f(mrow - nm);
        mrow = nm;
        float pv[4][4];
        float rs = 0.f;
        #pragma unroll
        for (int fc = 0; fc < 4; ++fc)
            #pragma unroll
            for (int r = 0; r < 4; ++r) {
                float p = __builtin_amdgcn_exp2f(sc[fc][r] - nm);
                pv[fc][r] = p;
                rs += p;
            }
        rs += __shfl_xor(rs, 16, 64);
        rs += __shfl_xor(rs, 32, 64);
        lrow = lrow * alpha + rs;
        #pragma unroll
        for (int f = 0; f < 4; f++)
            #pragma unroll
            for (int r = 0; r < 4; r++) oacc[f][r] *= alpha;

        lds_fence();   // this tile's T reads retired before P overwrites alias
        #pragma unroll
        for (int fc = 0; fc < 4; ++fc) {
            uint2 u;
            u.x = cvt_pk_bf16(pv[fc][0], pv[fc][1]);
            u.y = cvt_pk_bf16(pv[fc][2], pv[fc][3]);
            *(uint2*)(pw + 16 * fc) = u;
        }
        lds_fence();
        bf16x8 pfr[2];
        pfr[0] = *(const bf16x8*)(prd);
        pfr[1] = *(const bf16x8*)(prd + 32);

        #pragma unroll
        for (int kk = 0; kk < 2; ++kk)
            #pragma unroll
            for (int fa = 0; fa < 4; ++fa) {
                bf16x8 vfr = *(const bf16x8*)&vbuf[(16 * fa + l16) * 64 + (kk ? gx1 : gx0)];
                oacc[fa] = __builtin_amdgcn_mfma_f32_16x16x32_bf16(vfr, pfr[kk], oacc[fa], 0, 0, 0);
            }
    };

    auto tile_pure = [&](auto mc, int ct, bool dz) __attribute__((always_inline)) {
        constexpr int MODE = decltype(mc)::value;   // 0: c<q, 1: c>q
        const int c0 = ct << 6;
        const int mb = c0 - q0 + 2032 - 16 * w + l16;

        f32x4 cacc[4];
        #pragma unroll
        for (int f = 0; f < 4; f++) cacc[f] = (f32x4){0.f, 0.f, 0.f, 0.f};
        #pragma unroll
        for (int fc = 0; fc < 4; ++fc) {
            bf16x8 k0v = *(const bf16x8*)&Kb[(16 * fc + l16) * 64 + gx0];
            bf16x8 k1v = *(const bf16x8*)&Kb[(16 * fc + l16) * 64 + gx1];
            cacc[fc] = __builtin_amdgcn_mfma_f32_16x16x32_bf16(k0v, qf0[0], cacc[fc], 0, 0, 0);
            cacc[fc] = __builtin_amdgcn_mfma_f32_16x16x32_bf16(k1v, qf0[1], cacc[fc], 0, 0, 0);
        }

        f32x4 tacc[5];
        #pragma unroll
        for (int g = 0; g < 5; g++) tacc[g] = (f32x4){0.f, 0.f, 0.f, 0.f};
        #pragma unroll
        for (int cg = 0; cg < 5; ++cg) {
            int sb = ((mb + 16 * cg) & 255) * 64;
            bf16x8 p0 = *(const bf16x8*)&P2b[sb + gx0];
            bf16x8 p1 = *(const bf16x8*)&P2b[sb + gx1];
            tacc[cg] = __builtin_amdgcn_mfma_f32_16x16x32_bf16(
                p0, (MODE == 1) ? qf1[0] : qf0[0], tacc[cg], 0, 0, 0);
            tacc[cg] = __builtin_amdgcn_mfma_f32_16x16x32_bf16(
                p1, (MODE == 1) ? qf1[1] : qf0[1], tacc[cg], 0, 0, 0);
        }

        __syncthreads();   // all waves done reading Kb / V(prev stage safe) / ring
        if (ct < 31) {
            stage_K(c0 + 64);
            stage_V(c0 + 64, (ct & 1) ^ 1);
            stage_P2(W0 + 192 + 64 * ct);
        }

        lds_fence();   // prior-tile P reads retired before T overwrites alias
        #pragma unroll
        for (int cg = 0; cg < 5; ++cg) {
            uint2 u;
            u.x = cvt_pk_bf16(tacc[cg][0], tacc[cg][1]);
            u.y = cvt_pk_bf16(tacc[cg][2], tacc[cg][3]);
            *(uint2*)(tw + 16 * cg) = u;
        }
        lds_fence();

        float sc[4][4];
        #pragma unroll
        for (int fc = 0; fc < 4; ++fc)
            #pragma unroll
            for (int r = 0; r < 4; ++r)
                sc[fc][r] = cacc[fc][r] + bf2f(tr[16 * fc + r]);
        if (MODE == 1 && dz && w == 7 && l16 == 15 && lq == 0)
            sc[0][0] = cacc[0][0];   // c == q+1 position: zero pos term

        finish(sc, &Vb[(ct & 1) * 4096]);
        __syncthreads();   // staged K/V/ring landed
    };

    auto tile_dual = [&](int ct) __attribute__((always_inline)) {
        const int c0 = ct << 6;
        const int mb = c0 - q0 + 2032 - 16 * w + l16;
        const int rel = q0 + gq_rel - c0;   // gq - c0

        f32x4 cacc[4];
        #pragma unroll
        for (int f = 0; f < 4; f++) cacc[f] = (f32x4){0.f, 0.f, 0.f, 0.f};
        #pragma unroll
        for (int fc = 0; fc < 4; ++fc) {
            bf16x8 k0v = *(const bf16x8*)&Kb[(16 * fc + l16) * 64 + gx0];
            bf16x8 k1v = *(const bf16x8*)&Kb[(16 * fc + l16) * 64 + gx1];
            cacc[fc] = __builtin_amdgcn_mfma_f32_16x16x32_bf16(k0v, qf0[0], cacc[fc], 0, 0, 0);
            cacc[fc] = __builtin_amdgcn_mfma_f32_16x16x32_bf16(k1v, qf0[1], cacc[fc], 0, 0, 0);
        }

        // pass A (su=0)
        f32x4 tacc[5];
        #pragma unroll
        for (int g = 0; g < 5; g++) tacc[g] = (f32x4){0.f, 0.f, 0.f, 0.f};
        #pragma unroll
        for (int cg = 0; cg < 5; ++cg) {
            int sb = ((mb + 16 * cg) & 255) * 64;
            bf16x8 p0 = *(const bf16x8*)&P2b[sb + gx0];
            bf16x8 p1 = *(const bf16x8*)&P2b[sb + gx1];
            tacc[cg] = __builtin_amdgcn_mfma_f32_16x16x32_bf16(p0, qf0[0], tacc[cg], 0, 0, 0);
            tacc[cg] = __builtin_amdgcn_mfma_f32_16x16x32_bf16(p1, qf0[1], tacc[cg], 0, 0, 0);
        }
        lds_fence();
        #pragma unroll
        for (int cg = 0; cg < 5; ++cg) {
            uint2 u;
            u.x = cvt_pk_bf16(tacc[cg][0], tacc[cg][1]);
            u.y = cvt_pk_bf16(tacc[cg][2], tacc[cg][3]);
            *(uint2*)(tw + 16 * cg) = u;
        }
        lds_fence();
        float v0[4][4];
        #pragma unroll
        for (int fc = 0; fc < 4; ++fc)
            #pragma unroll
            for (int r = 0; r < 4; ++r) v0[fc][r] = bf2f(tr[16 * fc + r]);
        lds_fence();   // v0 reads retired before pass-B T overwrite

        // pass B (su=1) — ring reads must precede the barrier
        f32x4 tb2[5];
        #pragma unroll
        for (int g = 0; g < 5; g++) tb2[g] = (f32x4){0.f, 0.f, 0.f, 0.f};
        #pragma unroll
        for (int cg = 0; cg < 5; ++cg) {
            int sb = ((mb + 16 * cg) & 255) * 64;
            bf16x8 p0 = *(const bf16x8*)&P2b[sb + gx0];
            bf16x8 p1 = *(const bf16x8*)&P2b[sb + gx1];
            tb2[cg] = __builtin_amdgcn_mfma_f32_16x16x32_bf16(p0, qf1[0], tb2[cg], 0, 0, 0);
            tb2[cg] = __builtin_amdgcn_mfma_f32_16x16x32_bf16(p1, qf1[1], tb2[cg], 0, 0, 0);
        }

        __syncthreads();   // all waves done reading Kb / ring (both passes)
        if (ct < 31) {
            stage_K(c0 + 64);
            stage_V(c0 + 64, (ct & 1) ^ 1);
            stage_P2(W0 + 192 + 64 * ct);
        }

        #pragma unroll
        for (int cg = 0; cg < 5; ++cg) {
            uint2 u;
            u.x = cvt_pk_bf16(tb2[cg][0], tb2[cg][1]);
            u.y = cvt_pk_bf16(tb2[cg][2], tb2[cg][3]);
            *(uint2*)(tw + 16 * cg) = u;
        }
        lds_fence();

        float sc[4][4];
        #pragma unroll
        for (int fc = 0; fc < 4; ++fc)
            #pragma unroll
            for (int r = 0; r < 4; ++r) {
                float vB = bf2f(tr[16 * fc + r]);
                int ci = 16 * fc + 4 * lq + r;
                float term = (ci == rel + 1) ? 0.f
                           : ((ci > rel) ? vB : v0[fc][r]);
                sc[fc][r] = cacc[fc][r] + term;
            }

        finish(sc, &Vb[(ct & 1) * 4096]);
        __syncthreads();
    };

    const int dct = 2 * qt;
    for (int ct = 0; ct < dct; ++ct) tile_pure(IC<0>{}, ct, false);
    tile_dual(dct);
    tile_dual(dct + 1);
    for (int ct = dct + 2; ct < S_LEN / 64; ++ct)
        tile_pure(IC<1>{}, ct, ct == dct + 2);

    // epilogue: lane owns row q0+gq_rel; 4 consecutive dh -> packed 8B stores
    const int b = bh >> 4, h = bh & 15;
    const float rinv = 1.0f / lrow;
    unsigned short* op = CTX + ((long)(b * S_LEN + q0 + gq_rel) * NHEADS + h) * DHEAD + 4 * lq;
    #pragma unroll
    for (int fa = 0; fa < 4; ++fa) {
        uint2 u;
        u.x = cvt_pk_bf16(oacc[fa][0] * rinv, oacc[fa][1] * rinv);
        u.y = cvt_pk_bf16(oacc[fa][2] * rinv, oacc[fa][3] * rinv);
        *(uint2*)(op + 16 * fa) = u;
    }
}

// ---------------------------------------------------------------------------
// Kernel 3: output GEMM.  out = ctx(bf16) @ Wo^T + bo, fp32 out.
// ---------------------------------------------------------------------------
__global__ __launch_bounds__(256) void out_gemm(
    const unsigned short* __restrict__ A,
    const float* __restrict__ W,
    const float* __restrict__ Bv,
    float* __restrict__ O)
{
    __shared__ __align__(16) unsigned short At[128 * 40];
    __shared__ __align__(16) unsigned short Bt[128 * 40];

    const int tid  = threadIdx.x;
    const int lane = tid & 63;
    const int w    = tid >> 6;
    const int wr   = w & 1, wc = w >> 1;
    const int m0   = blockIdx.x * 128;
    const int n0   = blockIdx.y * 128;
    const int l16  = lane & 15, lq = lane >> 4;

    f32x4 acc[4][4];
    #pragma unroll
    for (int i = 0; i < 4; i++)
        #pragma unroll
        for (int j = 0; j < 4; j++) acc[i][j] = (f32x4){0.f, 0.f, 0.f, 0.f};

    for (int k0 = 0; k0 < DMODEL; k0 += 32) {
        __syncthreads();
        #pragma unroll
        for (int i = 0; i < 2; i++) {
            int e = tid + i * 256;
            int row = e >> 2, sg = e & 3;
            *(float4*)&At[row * 40 + sg * 8] =
                *(const float4*)&A[(long)(m0 + row) * DMODEL + k0 + sg * 8];
        }
        #pragma unroll
        for (int i = 0; i < 4; i++) {
            int e = tid + i * 256;
            int row = e >> 3, cg = e & 7;
            float4 vb = *(const float4*)&W[(long)(n0 + row) * DMODEL + k0 + cg * 4];
            uint2 ub; ub.x = cvt_pk_bf16(vb.x, vb.y); ub.y = cvt_pk_bf16(vb.z, vb.w);
            *(uint2*)&Bt[row * 40 + cg * 4] = ub;
        }
        __syncthreads();
        bf16x8 af[4], bfr[4];
        #pragma unroll
        for (int f = 0; f < 4; f++) {
            af[f]  = *(const bf16x8*)&At[(64 * wr + 16 * f + l16) * 40 + 8 * lq];
            bfr[f] = *(const bf16x8*)&Bt[(64 * wc + 16 * f + l16) * 40 + 8 * lq];
        }
        #pragma unroll
        for (int i = 0; i < 4; i++)
            #pragma unroll
            for (int j = 0; j < 4; j++)
                acc[i][j] = __builtin_amdgcn_mfma_f32_16x16x32_bf16(af[i], bfr[j], acc[i][j], 0, 0, 0);
    }

    #pragma unroll
    for (int j = 0; j < 4; j++) {
        int n_g = n0 + 64 * wc + 16 * j + l16;
        float bias = Bv[n_g];
        #pragma unroll
        for (int i = 0; i < 4; i++) {
            #pragma unroll
            for (int r = 0; r < 4; r++) {
                int m_g = m0 + 64 * wr + 16 * i + 4 * lq + r;
                O[(long)m_g * DMODEL + n_g] = acc[i][j][r] + bias;
            }
        }
    }
}

// ---------------------------------------------------------------------------
extern "C" void kernel_launch(void* const* d_in, const int* in_sizes, int n_in,
                              void* d_out, int out_size, void* d_ws, size_t ws_size,
                              hipStream_t stream) {
    (void)in_sizes; (void)n_in; (void)out_size; (void)ws_size;
    const float* query = (const float*)d_in[0];
    const float* key_  = (const float*)d_in[1];
    const float* value = (const float*)d_in[2];
    const float* pos   = (const float*)d_in[3];
    const float* Wq = (const float*)d_in[4];  const float* bq = (const float*)d_in[5];
    const float* Wk = (const float*)d_in[6];  const float* bk = (const float*)d_in[7];
    const float* Wv = (const float*)d_in[8];  const float* bv = (const float*)d_in[9];
    const float* Wp = (const float*)d_in[10]; const float* bp = (const float*)d_in[11];
    const float* Wo = (const float*)d_in[12]; const float* bo = (const float*)d_in[13];
    float* out = (float*)d_out;

    const long NE = (long)TOKENS * DMODEL;   // 4,194,304 elements per tensor
    unsigned short* qb = (unsigned short*)d_ws;
    unsigned short* kb = qb + NE;
    unsigned short* vb = kb + NE;            // V^T layout [BH][64][S]
    unsigned short* pb = vb + NE;            // plain p table [BH][S][64]
    unsigned short* cx = pb + NE;            // total ws use: 5 * 8 MB = 40 MB

    proj_gemm<<<dim3(32, 8, 4), 256, 0, stream>>>(
        query, key_, value, pos, Wq, Wk, Wv, Wp, bq, bk, bv, bp, qb, kb, vb, pb);
    rel_attn<<<512, 512, 0, stream>>>(qb, kb, vb, pb, cx);
    out_gemm<<<dim3(32, 8), 256, 0, stream>>>(cx, Wo, bo, out);
}

// Round 12
// 231.666 us; speedup vs baseline: 1.5369x; 1.0855x over previous
//
#include <hip/hip_runtime.h>
#include <hip/hip_bf16.h>

// Problem constants (fixed by harness setup_inputs).
#define S_LEN  2048
#define DMODEL 1024
#define NHEADS 16
#define DHEAD  64
#define TOKENS 4096   // B*S
#define QSCALE 0.04508422f   // (1/32) * log2(e): scores come out in log2 domain

typedef __attribute__((ext_vector_type(8))) short bf16x8;
typedef __attribute__((ext_vector_type(4))) float f32x4;

template <int M> struct IC { static constexpr int value = M; };

__device__ __forceinline__ float bf2f(unsigned short b) {
    union { unsigned u; float f; } v; v.u = ((unsigned)b) << 16;
    return v.f;
}
__device__ __forceinline__ unsigned cvt_pk_bf16(float lo, float hi) {
    unsigned r;
    asm("v_cvt_pk_bf16_f32 %0, %1, %2" : "=v"(r) : "v"(lo), "v"(hi));
    return r;
}
__device__ __forceinline__ unsigned short f2bf1(float x) {
    return (unsigned short)cvt_pk_bf16(x, x);
}
// wave-local LDS ordering fence (guards wave-private T/P roundtrips).
__device__ __forceinline__ void lds_fence() {
    asm volatile("s_waitcnt lgkmcnt(0)" ::: "memory");
    __builtin_amdgcn_sched_barrier(0);
}
// global -> LDS DMA, 16B per lane. LDS dest = wave-uniform base + lane*16;
// global src is per-lane (enables source-side swizzle).
__device__ __forceinline__ void gload_lds16(const void* g, void* l) {
    __builtin_amdgcn_global_load_lds(
        (const __attribute__((address_space(1))) void*)g,
        (__attribute__((address_space(3))) void*)l, 16, 0, 0);
}

// ---------------------------------------------------------------------------
// Kernel 1: fused 4-way projection GEMM.  out = X @ W^T + b  (bf16).
// Register-prefetch double buffer: next K-slab global loads issue right
// after the LDS-ready barrier, hiding ~500cy latency under the MFMA phase.
// z=0 (q): scaled by QSCALE, layout [BH][S][64]
// z=1 (k), z=3 (p): layout [BH][S][64]
// z=2 (v): layout [BH][64][S]  (transposed, packed b64 stores)
// ---------------------------------------------------------------------------
__global__ __launch_bounds__(256) void proj_gemm(
    const float* __restrict__ x0, const float* __restrict__ x1,
    const float* __restrict__ x2, const float* __restrict__ x3,
    const float* __restrict__ w0, const float* __restrict__ w1,
    const float* __restrict__ w2, const float* __restrict__ w3,
    const float* __restrict__ b0, const float* __restrict__ b1,
    const float* __restrict__ b2, const float* __restrict__ b3,
    unsigned short* __restrict__ o0, unsigned short* __restrict__ o1,
    unsigned short* __restrict__ o2, unsigned short* __restrict__ o3)
{
    const int z = blockIdx.z;
    const float* X  = (z == 0) ? x0 : (z == 1) ? x1 : (z == 2) ? x2 : x3;
    const float* W  = (z == 0) ? w0 : (z == 1) ? w1 : (z == 2) ? w2 : w3;
    const float* Bv = (z == 0) ? b0 : (z == 1) ? b1 : (z == 2) ? b2 : b3;
    unsigned short* O = (z == 0) ? o0 : (z == 1) ? o1 : (z == 2) ? o2 : o3;

    __shared__ __align__(16) unsigned short At[128 * 40];
    __shared__ __align__(16) unsigned short Bt[128 * 40];

    const int tid  = threadIdx.x;
    const int lane = tid & 63;
    const int w    = tid >> 6;
    const int wr   = w & 1, wc = w >> 1;
    const int m0   = blockIdx.x * 128;
    const int n0   = blockIdx.y * 128;
    const int l16  = lane & 15, lq = lane >> 4;

    f32x4 acc[4][4];
    #pragma unroll
    for (int i = 0; i < 4; i++)
        #pragma unroll
        for (int j = 0; j < 4; j++) acc[i][j] = (f32x4){0.f, 0.f, 0.f, 0.f};

    // prefetch slab k0=0 into registers
    float4 ra[4], rb[4];
    #pragma unroll
    for (int i = 0; i < 4; i++) {
        int e = tid + i * 256, row = e >> 3, cg = e & 7;
        ra[i] = *(const float4*)&X[(long)(m0 + row) * DMODEL + cg * 4];
        rb[i] = *(const float4*)&W[(long)(n0 + row) * DMODEL + cg * 4];
    }

    for (int k0 = 0; k0 < DMODEL; k0 += 32) {
        __syncthreads();   // previous iteration's fragment reads done
        #pragma unroll
        for (int i = 0; i < 4; i++) {
            int e = tid + i * 256, row = e >> 3, cg = e & 7;
            uint2 ua; ua.x = cvt_pk_bf16(ra[i].x, ra[i].y); ua.y = cvt_pk_bf16(ra[i].z, ra[i].w);
            *(uint2*)&At[row * 40 + cg * 4] = ua;
            uint2 ub; ub.x = cvt_pk_bf16(rb[i].x, rb[i].y); ub.y = cvt_pk_bf16(rb[i].z, rb[i].w);
            *(uint2*)&Bt[row * 40 + cg * 4] = ub;
        }
        __syncthreads();   // LDS tiles ready
        if (k0 + 32 < DMODEL) {
            #pragma unroll
            for (int i = 0; i < 4; i++) {
                int e = tid + i * 256, row = e >> 3, cg = e & 7;
                ra[i] = *(const float4*)&X[(long)(m0 + row) * DMODEL + k0 + 32 + cg * 4];
                rb[i] = *(const float4*)&W[(long)(n0 + row) * DMODEL + k0 + 32 + cg * 4];
            }
        }
        bf16x8 af[4], bfr[4];
        #pragma unroll
        for (int f = 0; f < 4; f++) {
            af[f]  = *(const bf16x8*)&At[(64 * wr + 16 * f + l16) * 40 + 8 * lq];
            bfr[f] = *(const bf16x8*)&Bt[(64 * wc + 16 * f + l16) * 40 + 8 * lq];
        }
        #pragma unroll
        for (int i = 0; i < 4; i++)
            #pragma unroll
            for (int j = 0; j < 4; j++)
                acc[i][j] = __builtin_amdgcn_mfma_f32_16x16x32_bf16(af[i], bfr[j], acc[i][j], 0, 0, 0);
    }

    #pragma unroll
    for (int j = 0; j < 4; j++) {
        int n_g = n0 + 64 * wc + 16 * j + l16;
        float bias = Bv[n_g];
        int h = n_g >> 6, dh = n_g & 63;
        if (z == 2) {
            #pragma unroll
            for (int i = 0; i < 4; i++) {
                int m_g = m0 + 64 * wr + 16 * i + 4 * lq;
                int b = m_g >> 11, s = m_g & (S_LEN - 1);
                uint2 u;
                u.x = cvt_pk_bf16(acc[i][j][0] + bias, acc[i][j][1] + bias);
                u.y = cvt_pk_bf16(acc[i][j][2] + bias, acc[i][j][3] + bias);
                *(uint2*)&O[(long)(((b * NHEADS + h) * DHEAD) + dh) * S_LEN + s] = u;
            }
        } else {
            float scale = (z == 0) ? QSCALE : 1.0f;
            #pragma unroll
            for (int i = 0; i < 4; i++) {
                #pragma unroll
                for (int r = 0; r < 4; r++) {
                    int m_g = m0 + 64 * wr + 16 * i + 4 * lq + r;
                    int b = m_g >> 11, s = m_g & (S_LEN - 1);
                    O[(long)(((b * NHEADS + h) * S_LEN) + s) * DHEAD + dh] =
                        f2bf1((acc[i][j][r] + bias) * scale);
                }
            }
        }
    }
}

// ---------------------------------------------------------------------------
// Kernel 2: fused relative-position flash attention, 8 waves, QB=128.
// ROUND-9 TEXT VERBATIM (last-known-good: passed, 154 us). K staged in LDS,
// V double-buffered LDS, 256-row P2 ring, per-wave T/P alias, 2 barriers/tile.
// ---------------------------------------------------------------------------
__global__ __launch_bounds__(512, 4) void rel_attn(
    const unsigned short* __restrict__ Q,    // [BH][S][64] bf16, pre-scaled
    const unsigned short* __restrict__ K,    // [BH][S][64]
    const unsigned short* __restrict__ VT,   // [BH][64][S]
    const unsigned short* __restrict__ P,    // [BH][S][64] plain p table
    unsigned short* __restrict__ CTX)        // [B][S][H][64] bf16
{
    __shared__ __align__(16) unsigned short Kb[64 * 64];      // 8 KB
    __shared__ __align__(16) unsigned short Vb[2 * 64 * 64];  // 16 KB dbuf
    __shared__ __align__(16) unsigned short P2b[256 * 64];    // 32 KB ring
    __shared__ __align__(16) unsigned short WPb[8 * 1344];    // per-wave T(16x84)/P(16x72)

    const int tid  = threadIdx.x;
    const int lane = tid & 63;
    const int w    = tid >> 6;          // 0..7
    const int l16  = lane & 15;
    const int lq   = lane >> 4;

    const int wg = ((blockIdx.x & 7) << 6) | (blockIdx.x >> 3);  // XCD swizzle (512 = 8*64)
    const int qt = wg & 15;
    const int bh = wg >> 4;
    const int q0 = qt << 7;             // 128 q-rows per block
    const long baseQK = (long)bh * (S_LEN * DHEAD);
    const int gq_rel = 16 * w + l16;    // q-row within block (0..127)

    const unsigned short* Kbh = K + baseQK;
    const unsigned short* Pbh = P + baseQK;
    const unsigned short* Vbh = VT + baseQK;

    // swizzled granule offsets for fragment reads (shorts); row&7 == l16&7
    const int gx0 = ((0 + lq) ^ (l16 & 7)) * 8;
    const int gx1 = ((4 + lq) ^ (l16 & 7)) * 8;

    // hoisted Q fragments: rows q0+gq_rel and +1 (row-2048 OOB read stays in
    // ws and only feeds pass-B values the select discards)
    bf16x8 qf0[2], qf1[2];
    {
        const unsigned short* qrow = Q + baseQK + (long)(q0 + gq_rel) * DHEAD + 8 * lq;
        qf0[0] = *(const bf16x8*)(qrow);
        qf0[1] = *(const bf16x8*)(qrow + 32);
        qf1[0] = *(const bf16x8*)(qrow + DHEAD);
        qf1[1] = *(const bf16x8*)(qrow + DHEAD + 32);
    }

    // staging: 64 rows / 8KB per stage = 1 gload per thread (512 x 16B)
    const int srow = lane >> 3;            // row-within-8 == row&7
    const int sgr  = (lane & 7) ^ srow;    // pre-swizzled source granule
    auto stage_K = [&](int kr0) __attribute__((always_inline)) {
        const unsigned short* src = Kbh + (long)(kr0 + w * 8 + srow) * 64 + sgr * 8;
        gload_lds16(src, &Kb[(w * 8) * 64]);
    };
    auto stage_V = [&](int c0, int buf) __attribute__((always_inline)) {
        // V tile rows = dh (0..63), row data = VT[bh][dh][c0..c0+63]
        const unsigned short* src = Vbh + (long)(w * 8 + srow) * S_LEN + c0 + sgr * 8;
        gload_lds16(src, &Vb[buf * 4096 + (w * 8) * 64]);
    };
    auto stage_P2 = [&](int mfirst) __attribute__((always_inline)) {   // mfirst % 64 == 0
        int m = mfirst + w * 8 + srow;
        int pr = m - ((m >= 2049) ? 2049 : 0);   // wrap; m==2048 garbage discarded later
        const unsigned short* src = Pbh + (long)pr * 64 + sgr * 8;
        gload_lds16(src, &P2b[(((mfirst & 255)) + w * 8) * 64]);
    };

    float mrow = -1e30f, lrow = 0.f;
    f32x4 oacc[4];
    #pragma unroll
    for (int f = 0; f < 4; f++) oacc[f] = (f32x4){0.f, 0.f, 0.f, 0.f};

    unsigned short* tw        = &WPb[w * 1344 + l16 * 84 + 4 * lq];
    const unsigned short* tr  = &WPb[w * 1344 + l16 * 83 + 15 + 4 * lq];
    unsigned short* pw        = &WPb[w * 1344 + l16 * 72 + 4 * lq];
    const unsigned short* prd = &WPb[w * 1344 + l16 * 72 + 8 * lq];

    const int W0 = 1920 - q0;   // lowest P2-window row of tile 0
    stage_K(0);
    stage_V(0, 0);
    stage_P2(W0); stage_P2(W0 + 64); stage_P2(W0 + 128);
    __syncthreads();

    // softmax + LDS P roundtrip + PV (V fragments from LDS)
    auto finish = [&](float (&sc)[4][4], const unsigned short* vbuf) __attribute__((always_inline)) {
        float tmax = sc[0][0];
        #pragma unroll
        for (int fc = 0; fc < 4; ++fc)
            #pragma unroll
            for (int r = 0; r < 4; ++r) tmax = fmaxf(tmax, sc[fc][r]);
        tmax = fmaxf(tmax, __shfl_xor(tmax, 16, 64));
        tmax = fmaxf(tmax, __shfl_xor(tmax, 32, 64));
        float nm = fmaxf(mrow, tmax);
        float alpha = __builtin_amdgcn_exp2f(mrow - nm);
        mrow = nm;
        float pv[4][4];
        float rs = 0.f;
        #pragma unroll
        for (int fc = 0; fc < 4; ++fc)
            #pragma unroll
            for (int r = 0; r < 4; ++r) {
                float p = __builtin_amdgcn_exp2f(sc[fc][r] - nm);
                pv[fc][r] = p;
                rs += p;
            }
        rs += __shfl_xor(rs, 16, 64);
        rs += __shfl_xor(rs, 32, 64);
        lrow = lrow * alpha + rs;
        #pragma unroll
        for (int f = 0; f < 4; f++)
            #pragma unroll
            for (int r = 0; r < 4; r++) oacc[f][r] *= alpha;

        lds_fence();   // this tile's T reads retired before P overwrites alias
        #pragma unroll
        for (int fc = 0; fc < 4; ++fc) {
            uint2 u;
            u.x = cvt_pk_bf16(pv[fc][0], pv[fc][1]);
            u.y = cvt_pk_bf16(pv[fc][2], pv[fc][3]);
            *(uint2*)(pw + 16 * fc) = u;
        }
        lds_fence();
        bf16x8 pfr[2];
        pfr[0] = *(const bf16x8*)(prd);
        pfr[1] = *(const bf16x8*)(prd + 32);

        #pragma unroll
        for (int kk = 0; kk < 2; ++kk)
            #pragma unroll
            for (int fa = 0; fa < 4; ++fa) {
                bf16x8 vfr = *(const bf16x8*)&vbuf[(16 * fa + l16) * 64 + (kk ? gx1 : gx0)];
                oacc[fa] = __builtin_amdgcn_mfma_f32_16x16x32_bf16(vfr, pfr[kk], oacc[fa], 0, 0, 0);
            }
    };

    auto tile_pure = [&](auto mc, int ct, bool dz) __attribute__((always_inline)) {
        constexpr int MODE = decltype(mc)::value;   // 0: c<q, 1: c>q
        const int c0 = ct << 6;
        const int mb = c0 - q0 + 2032 - 16 * w + l16;

        f32x4 cacc[4];
        #pragma unroll
        for (int f = 0; f < 4; f++) cacc[f] = (f32x4){0.f, 0.f, 0.f, 0.f};
        #pragma unroll
        for (int fc = 0; fc < 4; ++fc) {
            bf16x8 k0v = *(const bf16x8*)&Kb[(16 * fc + l16) * 64 + gx0];
            bf16x8 k1v = *(const bf16x8*)&Kb[(16 * fc + l16) * 64 + gx1];
            cacc[fc] = __builtin_amdgcn_mfma_f32_16x16x32_bf16(k0v, qf0[0], cacc[fc], 0, 0, 0);
            cacc[fc] = __builtin_amdgcn_mfma_f32_16x16x32_bf16(k1v, qf0[1], cacc[fc], 0, 0, 0);
        }

        f32x4 tacc[5];
        #pragma unroll
        for (int g = 0; g < 5; g++) tacc[g] = (f32x4){0.f, 0.f, 0.f, 0.f};
        #pragma unroll
        for (int cg = 0; cg < 5; ++cg) {
            int sb = ((mb + 16 * cg) & 255) * 64;
            bf16x8 p0 = *(const bf16x8*)&P2b[sb + gx0];
            bf16x8 p1 = *(const bf16x8*)&P2b[sb + gx1];
            tacc[cg] = __builtin_amdgcn_mfma_f32_16x16x32_bf16(
                p0, (MODE == 1) ? qf1[0] : qf0[0], tacc[cg], 0, 0, 0);
            tacc[cg] = __builtin_amdgcn_mfma_f32_16x16x32_bf16(
                p1, (MODE == 1) ? qf1[1] : qf0[1], tacc[cg], 0, 0, 0);
        }

        __syncthreads();   // all waves done reading Kb / V(prev stage safe) / ring
        if (ct < 31) {
            stage_K(c0 + 64);
            stage_V(c0 + 64, (ct & 1) ^ 1);
            stage_P2(W0 + 192 + 64 * ct);
        }

        lds_fence();   // prior-tile P reads retired before T overwrites alias
        #pragma unroll
        for (int cg = 0; cg < 5; ++cg) {
            uint2 u;
            u.x = cvt_pk_bf16(tacc[cg][0], tacc[cg][1]);
            u.y = cvt_pk_bf16(tacc[cg][2], tacc[cg][3]);
            *(uint2*)(tw + 16 * cg) = u;
        }
        lds_fence();

        float sc[4][4];
        #pragma unroll
        for (int fc = 0; fc < 4; ++fc)
            #pragma unroll
            for (int r = 0; r < 4; ++r)
                sc[fc][r] = cacc[fc][r] + bf2f(tr[16 * fc + r]);
        if (MODE == 1 && dz && w == 7 && l16 == 15 && lq == 0)
            sc[0][0] = cacc[0][0];   // c == q+1 position: zero pos term

        finish(sc, &Vb[(ct & 1) * 4096]);
        __syncthreads();   // staged K/V/ring landed
    };

    auto tile_dual = [&](int ct) __attribute__((always_inline)) {
        const int c0 = ct << 6;
        const int mb = c0 - q0 + 2032 - 16 * w + l16;
        const int rel = q0 + gq_rel - c0;   // gq - c0

        f32x4 cacc[4];
        #pragma unroll
        for (int f = 0; f < 4; f++) cacc[f] = (f32x4){0.f, 0.f, 0.f, 0.f};
        #pragma unroll
        for (int fc = 0; fc < 4; ++fc) {
            bf16x8 k0v = *(const bf16x8*)&Kb[(16 * fc + l16) * 64 + gx0];
            bf16x8 k1v = *(const bf16x8*)&Kb[(16 * fc + l16) * 64 + gx1];
            cacc[fc] = __builtin_amdgcn_mfma_f32_16x16x32_bf16(k0v, qf0[0], cacc[fc], 0, 0, 0);
            cacc[fc] = __builtin_amdgcn_mfma_f32_16x16x32_bf16(k1v, qf0[1], cacc[fc], 0, 0, 0);
        }

        // pass A (su=0)
        f32x4 tacc[5];
        #pragma unroll
        for (int g = 0; g < 5; g++) tacc[g] = (f32x4){0.f, 0.f, 0.f, 0.f};
        #pragma unroll
        for (int cg = 0; cg < 5; ++cg) {
            int sb = ((mb + 16 * cg) & 255) * 64;
            bf16x8 p0 = *(const bf16x8*)&P2b[sb + gx0];
            bf16x8 p1 = *(const bf16x8*)&P2b[sb + gx1];
            tacc[cg] = __builtin_amdgcn_mfma_f32_16x16x32_bf16(p0, qf0[0], tacc[cg], 0, 0, 0);
            tacc[cg] = __builtin_amdgcn_mfma_f32_16x16x32_bf16(p1, qf0[1], tacc[cg], 0, 0, 0);
        }
        lds_fence();
        #pragma unroll
        for (int cg = 0; cg < 5; ++cg) {
            uint2 u;
            u.x = cvt_pk_bf16(tacc[cg][0], tacc[cg][1]);
            u.y = cvt_pk_bf16(tacc[cg][2], tacc[cg][3]);
            *(uint2*)(tw + 16 * cg) = u;
        }
        lds_fence();
        float v0[4][4];
        #pragma unroll
        for (int fc = 0; fc < 4; ++fc)
            #pragma unroll
            for (int r = 0; r < 4; ++r) v0[fc][r] = bf2f(tr[16 * fc + r]);
        lds_fence();   // v0 reads retired before pass-B T overwrite

        // pass B (su=1) — ring reads must precede the barrier
        f32x4 tb2[5];
        #pragma unroll
        for (int g = 0; g < 5; g++) tb2[g] = (f32x4){0.f, 0.f, 0.f, 0.f};
        #pragma unroll
        for (int cg = 0; cg < 5; ++cg) {
            int sb = ((mb + 16 * cg) & 255) * 64;
            bf16x8 p0 = *(const bf16x8*)&P2b[sb + gx0];
            bf16x8 p1 = *(const bf16x8*)&P2b[sb + gx1];
            tb2[cg] = __builtin_amdgcn_mfma_f32_16x16x32_bf16(p0, qf1[0], tb2[cg], 0, 0, 0);
            tb2[cg] = __builtin_amdgcn_mfma_f32_16x16x32_bf16(p1, qf1[1], tb2[cg], 0, 0, 0);
        }

        __syncthreads();   // all waves done reading Kb / ring (both passes)
        if (ct < 31) {
            stage_K(c0 + 64);
            stage_V(c0 + 64, (ct & 1) ^ 1);
            stage_P2(W0 + 192 + 64 * ct);
        }

        #pragma unroll
        for (int cg = 0; cg < 5; ++cg) {
            uint2 u;
            u.x = cvt_pk_bf16(tb2[cg][0], tb2[cg][1]);
            u.y = cvt_pk_bf16(tb2[cg][2], tb2[cg][3]);
            *(uint2*)(tw + 16 * cg) = u;
        }
        lds_fence();

        float sc[4][4];
        #pragma unroll
        for (int fc = 0; fc < 4; ++fc)
            #pragma unroll
            for (int r = 0; r < 4; ++r) {
                float vB = bf2f(tr[16 * fc + r]);
                int ci = 16 * fc + 4 * lq + r;
                float term = (ci == rel + 1) ? 0.f
                           : ((ci > rel) ? vB : v0[fc][r]);
                sc[fc][r] = cacc[fc][r] + term;
            }

        finish(sc, &Vb[(ct & 1) * 4096]);
        __syncthreads();
    };

    const int dct = 2 * qt;
    for (int ct = 0; ct < dct; ++ct) tile_pure(IC<0>{}, ct, false);
    tile_dual(dct);
    tile_dual(dct + 1);
    for (int ct = dct + 2; ct < S_LEN / 64; ++ct)
        tile_pure(IC<1>{}, ct, ct == dct + 2);

    // epilogue: lane owns row q0+gq_rel; 4 consecutive dh -> packed 8B stores
    const int b = bh >> 4, h = bh & 15;
    const float rinv = 1.0f / lrow;
    unsigned short* op = CTX + ((long)(b * S_LEN + q0 + gq_rel) * NHEADS + h) * DHEAD + 4 * lq;
    #pragma unroll
    for (int fa = 0; fa < 4; ++fa) {
        uint2 u;
        u.x = cvt_pk_bf16(oacc[fa][0] * rinv, oacc[fa][1] * rinv);
        u.y = cvt_pk_bf16(oacc[fa][2] * rinv, oacc[fa][3] * rinv);
        *(uint2*)(op + 16 * fa) = u;
    }
}

// ---------------------------------------------------------------------------
// Kernel 3: output GEMM.  out = ctx(bf16) @ Wo^T + bo, fp32 out.
// Same register-prefetch double buffer as proj_gemm.
// ---------------------------------------------------------------------------
__global__ __launch_bounds__(256) void out_gemm(
    const unsigned short* __restrict__ A,
    const float* __restrict__ W,
    const float* __restrict__ Bv,
    float* __restrict__ O)
{
    __shared__ __align__(16) unsigned short At[128 * 40];
    __shared__ __align__(16) unsigned short Bt[128 * 40];

    const int tid  = threadIdx.x;
    const int lane = tid & 63;
    const int w    = tid >> 6;
    const int wr   = w & 1, wc = w >> 1;
    const int m0   = blockIdx.x * 128;
    const int n0   = blockIdx.y * 128;
    const int l16  = lane & 15, lq = lane >> 4;

    f32x4 acc[4][4];
    #pragma unroll
    for (int i = 0; i < 4; i++)
        #pragma unroll
        for (int j = 0; j < 4; j++) acc[i][j] = (f32x4){0.f, 0.f, 0.f, 0.f};

    float4 ra[2], rb[4];
    #pragma unroll
    for (int i = 0; i < 2; i++) {
        int e = tid + i * 256, row = e >> 2, sg = e & 3;
        ra[i] = *(const float4*)&A[(long)(m0 + row) * DMODEL + sg * 8];
    }
    #pragma unroll
    for (int i = 0; i < 4; i++) {
        int e = tid + i * 256, row = e >> 3, cg = e & 7;
        rb[i] = *(const float4*)&W[(long)(n0 + row) * DMODEL + cg * 4];
    }

    for (int k0 = 0; k0 < DMODEL; k0 += 32) {
        __syncthreads();
        #pragma unroll
        for (int i = 0; i < 2; i++) {
            int e = tid + i * 256, row = e >> 2, sg = e & 3;
            *(float4*)&At[row * 40 + sg * 8] = ra[i];
        }
        #pragma unroll
        for (int i = 0; i < 4; i++) {
            int e = tid + i * 256, row = e >> 3, cg = e & 7;
            uint2 ub; ub.x = cvt_pk_bf16(rb[i].x, rb[i].y); ub.y = cvt_pk_bf16(rb[i].z, rb[i].w);
            *(uint2*)&Bt[row * 40 + cg * 4] = ub;
        }
        __syncthreads();
        if (k0 + 32 < DMODEL) {
            #pragma unroll
            for (int i = 0; i < 2; i++) {
                int e = tid + i * 256, row = e >> 2, sg = e & 3;
                ra[i] = *(const float4*)&A[(long)(m0 + row) * DMODEL + k0 + 32 + sg * 8];
            }
            #pragma unroll
            for (int i = 0; i < 4; i++) {
                int e = tid + i * 256, row = e >> 3, cg = e & 7;
                rb[i] = *(const float4*)&W[(long)(n0 + row) * DMODEL + k0 + 32 + cg * 4];
            }
        }
        bf16x8 af[4], bfr[4];
        #pragma unroll
        for (int f = 0; f < 4; f++) {
            af[f]  = *(const bf16x8*)&At[(64 * wr + 16 * f + l16) * 40 + 8 * lq];
            bfr[f] = *(const bf16x8*)&Bt[(64 * wc + 16 * f + l16) * 40 + 8 * lq];
        }
        #pragma unroll
        for (int i = 0; i < 4; i++)
            #pragma unroll
            for (int j = 0; j < 4; j++)
                acc[i][j] = __builtin_amdgcn_mfma_f32_16x16x32_bf16(af[i], bfr[j], acc[i][j], 0, 0, 0);
    }

    #pragma unroll
    for (int j = 0; j < 4; j++) {
        int n_g = n0 + 64 * wc + 16 * j + l16;
        float bias = Bv[n_g];
        #pragma unroll
        for (int i = 0; i < 4; i++) {
            #pragma unroll
            for (int r = 0; r < 4; r++) {
                int m_g = m0 + 64 * wr + 16 * i + 4 * lq + r;
                O[(long)m_g * DMODEL + n_g] = acc[i][j][r] + bias;
            }
        }
    }
}

// ---------------------------------------------------------------------------
extern "C" void kernel_launch(void* const* d_in, const int* in_sizes, int n_in,
                              void* d_out, int out_size, void* d_ws, size_t ws_size,
                              hipStream_t stream) {
    (void)in_sizes; (void)n_in; (void)out_size; (void)ws_size;
    const float* query = (const float*)d_in[0];
    const float* key_  = (const float*)d_in[1];
    const float* value = (const float*)d_in[2];
    const float* pos   = (const float*)d_in[3];
    const float* Wq = (const float*)d_in[4];  const float* bq = (const float*)d_in[5];
    const float* Wk = (const float*)d_in[6];  const float* bk = (const float*)d_in[7];
    const float* Wv = (const float*)d_in[8];  const float* bv = (const float*)d_in[9];
    const float* Wp = (const float*)d_in[10]; const float* bp = (const float*)d_in[11];
    const float* Wo = (const float*)d_in[12]; const float* bo = (const float*)d_in[13];
    float* out = (float*)d_out;

    const long NE = (long)TOKENS * DMODEL;   // 4,194,304 elements per tensor
    unsigned short* qb = (unsigned short*)d_ws;
    unsigned short* kb = qb + NE;
    unsigned short* vb = kb + NE;            // V^T layout [BH][64][S]
    unsigned short* pb = vb + NE;            // plain p table [BH][S][64]
    unsigned short* cx = pb + NE;            // total ws use: 5 * 8 MB = 40 MB

    proj_gemm<<<dim3(32, 8, 4), 256, 0, stream>>>(
        query, key_, value, pos, Wq, Wk, Wv, Wp, bq, bk, bv, bp, qb, kb, vb, pb);
    rel_attn<<<512, 512, 0, stream>>>(qb, kb, vb, pb, cx);
    out_gemm<<<dim3(32, 8), 256, 0, stream>>>(cx, Wo, bo, out);
}